// Round 4
// baseline (4656.585 us; speedup 1.0000x reference)
//
#include <hip/hip_runtime.h>

// ReservoirLayer: S0 = pad(x,[2048,4096]); 16x: S = leaky_relu(S @ W, 0.1)
// fp32-emulation via fp16 hi/lo split (fp16x3): acc = Sh@Wh + Sl@Wh + Sh@Wl.
// R4: (a) A-operand bypasses LDS — wave-private fragments loaded straight to
// registers via global_load_dwordx4, prefetched one K-iter ahead (halves LDS
// traffic); (b) mfma 32x32x16 — half the MFMA instruction count, higher ceiling.
// B (=W^T hi/lo) still double-buffered in LDS via global_load_lds width-16.

#define BATCH 2048
#define NDIM  4096
#define INDIM 512
#define BM 128
#define BN 128
#define BK 32

typedef _Float16 f16x8  __attribute__((ext_vector_type(8)));
typedef float    f32x16 __attribute__((ext_vector_type(16)));

__device__ __forceinline__ void async16(const void* gsrc, void* ldst) {
  const __attribute__((address_space(1))) unsigned int* g =
      (const __attribute__((address_space(1))) unsigned int*)gsrc;
  __attribute__((address_space(3))) unsigned int* l =
      (__attribute__((address_space(3))) unsigned int*)ldst;
  __builtin_amdgcn_global_load_lds(g, l, 16, 0, 0);
}

// ---------------- prep: split+pad x into S_hi/S_lo ----------------
__global__ void prep_x(const float* __restrict__ x,
                       _Float16* __restrict__ Sh, _Float16* __restrict__ Sl) {
  size_t i = (size_t)blockIdx.x * 256 + threadIdx.x;  // over BATCH*NDIM
  int b = (int)(i >> 12);
  int n = (int)(i & (NDIM - 1));
  float v = (n < INDIM) ? x[(size_t)b * INDIM + n] : 0.0f;
  _Float16 h = (_Float16)v;
  Sh[i] = h;
  Sl[i] = (_Float16)(v - (float)h);
}

// ---------------- prep: transpose + scale(256) + split W ----------------
__global__ void prep_w(const float* __restrict__ W,
                       _Float16* __restrict__ Wth, _Float16* __restrict__ Wtl) {
  __shared__ float tile[32][33];
  int k0 = blockIdx.y * 32, n0 = blockIdx.x * 32;
  int tx = threadIdx.x, ty = threadIdx.y;  // 32 x 8
  for (int r = 0; r < 4; r++) {
    int k = k0 + ty + r * 8;
    tile[ty + r * 8][tx] = W[(size_t)k * NDIM + n0 + tx];
  }
  __syncthreads();
  for (int r = 0; r < 4; r++) {
    int n = n0 + ty + r * 8;
    float v = tile[tx][ty + r * 8] * 256.0f;
    _Float16 h = (_Float16)v;
    Wth[(size_t)n * NDIM + k0 + tx] = h;
    Wtl[(size_t)n * NDIM + k0 + tx] = (_Float16)(v - (float)h);
  }
}

#define LOADA(kt, AH, AL)                                    \
  do {                                                       \
    _Pragma("unroll") for (int i = 0; i < 2; i++)            \
    _Pragma("unroll") for (int s = 0; s < 2; s++) {          \
      AH[i][s] = *(const f16x8*)(Ah + gA[i] + (kt) + s * 16);\
      AL[i][s] = *(const f16x8*)(Al + gA[i] + (kt) + s * 16);\
    }                                                        \
  } while (0)

#define READB(b)                                             \
  do {                                                       \
    _Pragma("unroll") for (int j = 0; j < 2; j++)            \
    _Pragma("unroll") for (int s = 0; s < 2; s++) {          \
      bh[j][s] = *(const f16x8*)&sBh[b][oB[j][s]];           \
      bl[j][s] = *(const f16x8*)&sBl[b][oB[j][s]];           \
    }                                                        \
  } while (0)

#define MFMAS(AH, AL)                                                                        \
  do {                                                                                       \
    _Pragma("unroll") for (int j = 0; j < 2; j++)                                            \
    _Pragma("unroll") for (int i = 0; i < 2; i++)                                            \
    _Pragma("unroll") for (int s = 0; s < 2; s++) {                                          \
      acc[i][j] = __builtin_amdgcn_mfma_f32_32x32x16_f16(AH[i][s], bh[j][s], acc[i][j], 0, 0, 0); \
      acc[i][j] = __builtin_amdgcn_mfma_f32_32x32x16_f16(AL[i][s], bh[j][s], acc[i][j], 0, 0, 0); \
      acc[i][j] = __builtin_amdgcn_mfma_f32_32x32x16_f16(AH[i][s], bl[j][s], acc[i][j], 0, 0, 0); \
    }                                                                                        \
  } while (0)

// ---------------- one recurrence step ----------------
template <int MODE>
__global__ __launch_bounds__(256, 2) void step_kernel(
    const _Float16* __restrict__ Ah, const _Float16* __restrict__ Al,
    const _Float16* __restrict__ Bh, const _Float16* __restrict__ Bl,
    _Float16* __restrict__ Dh, _Float16* __restrict__ Dl,
    float* __restrict__ Dout, int k_len) {
  __shared__ _Float16 sBh[2][BN * BK];
  __shared__ _Float16 sBl[2][BN * BK];

  const int tid = threadIdx.x;
  const int lane = tid & 63;
  const int w = tid >> 6;
  const int wm = w >> 1, wn = w & 1;  // 2x2 wave grid, wave tile 64x64

  // XCD-aware swizzle: 8x8 block region per XCD (round-robin dispatch, id&7)
  int id = blockIdx.x;
  int xcd = id & 7, local = id >> 3;
  int lr = local & 7, lc = local >> 3;
  const int bm = ((xcd & 1) * 8 + lr) * BM;
  const int bn = ((xcd >> 1) * 8 + lc) * BN;

  const int l31 = lane & 31, l5 = lane >> 5;

  // B fragment LDS element-offsets (k-chunk XOR swizzle), loop-invariant.
  // 32x32x16 B operand: col = lane&31, k = (lane>>5)*8 + e; kstep s adds 16.
  int oB[2][2];
#pragma unroll
  for (int j = 0; j < 2; j++)
#pragma unroll
    for (int s = 0; s < 2; s++) {
      int row = wn * 64 + j * 32 + l31;
      int c = s * 2 + l5;
      oB[j][s] = row * BK + (c ^ ((row >> 1) & 3)) * 8;
    }

  // A global base element-offsets (wave-private rows; bypasses LDS).
  // 32x32x16 A operand: row = lane&31, k = (lane>>5)*8 + e.
  size_t gA[2];
#pragma unroll
  for (int i = 0; i < 2; i++)
    gA[i] = (size_t)(bm + wm * 64 + i * 32 + l31) * NDIM + l5 * 8;

  // B staging addresses (DMA, wave-uniform base + lane*16 on the LDS side)
  const int sr = lane >> 2, cl = lane & 3;
  const int r0 = w * 32 + sr, r1 = r0 + 16;
  const int cg0 = cl ^ ((r0 >> 1) & 3), cg1 = cl ^ ((r1 >> 1) & 3);
  const size_t gB0 = (size_t)(bn + r0) * NDIM + cg0 * 8;
  const size_t gB1 = (size_t)(bn + r1) * NDIM + cg1 * 8;
  const int lo0 = r0 * BK + cl * 8, lo1 = r1 * BK + cl * 8;

  auto stageB = [&](int kt, int b) {
    async16(Bh + gB0 + kt, &sBh[b][lo0]);
    async16(Bh + gB1 + kt, &sBh[b][lo1]);
    async16(Bl + gB0 + kt, &sBl[b][lo0]);
    async16(Bl + gB1 + kt, &sBl[b][lo1]);
  };

  f32x16 acc[2][2];
#pragma unroll
  for (int i = 0; i < 2; i++)
#pragma unroll
    for (int j = 0; j < 2; j++)
#pragma unroll
      for (int e = 0; e < 16; e++) acc[i][j][e] = 0.0f;

  f16x8 a0h[2][2], a0l[2][2], a1h[2][2], a1l[2][2];
  f16x8 bh[2][2], bl[2][2];

  const int nk = k_len / BK;  // 16 or 128 (even)

  // prologue: stage B tiles 0,1; fetch A frags for tile 0
  stageB(0, 0);
  stageB(BK, 1);
  LOADA(0, a0h, a0l);
  __syncthreads();  // one-time full drain (stages + A0)

  for (int it = 0; it < nk; it += 2) {
    // ---- iter it (B buf0, A set0); prefetch A(it+1)
    READB(0);
    LOADA((it + 1) * BK, a1h, a1l);
    MFMAS(a0h, a0l);
    __syncthreads();                      // drains stage(it+1) [1 iter old]
    if (it + 2 < nk) stageB((it + 2) * BK, 0);

    // ---- iter it+1 (B buf1, A set1); prefetch A(it+2)
    READB(1);
    if (it + 2 < nk) LOADA((it + 2) * BK, a0h, a0l);
    MFMAS(a1h, a1l);
    __syncthreads();                      // drains stage(it+2)
    if (it + 3 < nk) stageB((it + 3) * BK, 1);
  }

  // ---- epilogue: undo 256x W-scale, leaky relu, write next state / output
  // 32x32 C/D (verified m74/m101): col = lane&31, row = (e&3) + 8*(e>>2) + 4*(lane>>5)
  const float inv = 1.0f / 256.0f;
#pragma unroll
  for (int i = 0; i < 2; i++) {
#pragma unroll
    for (int j = 0; j < 2; j++) {
#pragma unroll
      for (int e = 0; e < 16; e++) {
        int r = bm + wm * 64 + i * 32 + (e & 3) + 8 * (e >> 2) + 4 * l5;
        int c = bn + wn * 64 + j * 32 + l31;
        float g = acc[i][j][e] * inv;
        float s = (g > 0.0f) ? g : 0.1f * g;
        if (MODE == 0) {
          _Float16 h = (_Float16)s;
          Dh[(size_t)r * NDIM + c] = h;
          Dl[(size_t)r * NDIM + c] = (_Float16)(s - (float)h);
        } else {
          Dout[(size_t)r * NDIM + c] = s;
        }
      }
    }
  }
}

extern "C" void kernel_launch(void* const* d_in, const int* in_sizes, int n_in,
                              void* d_out, int out_size, void* d_ws, size_t ws_size,
                              hipStream_t stream) {
  const float* x = (const float*)d_in[0];  // [2048, 512]
  const float* W = (const float*)d_in[1];  // [4096, 4096]
  float* out = (float*)d_out;              // [2048, 4096]
  char* ws = (char*)d_ws;

  const size_t WT_BYTES = (size_t)NDIM * NDIM * 2;  // 32 MB each
  const size_t S_BYTES = (size_t)BATCH * NDIM * 2;  // 16 MB each
  _Float16* Wth = (_Float16*)ws;
  _Float16* Wtl = (_Float16*)(ws + WT_BYTES);
  _Float16* SAh = (_Float16*)(ws + 2 * WT_BYTES);
  _Float16* SAl = (_Float16*)(ws + 2 * WT_BYTES + S_BYTES);
  _Float16* SBh = (_Float16*)(ws + 2 * WT_BYTES + 2 * S_BYTES);
  _Float16* SBl = (_Float16*)(ws + 2 * WT_BYTES + 3 * S_BYTES);

  prep_x<<<(BATCH * NDIM) / 256, 256, 0, stream>>>(x, SAh, SAl);
  prep_w<<<dim3(NDIM / 32, NDIM / 32), dim3(32, 8), 0, stream>>>(W, Wth, Wtl);

  dim3 grid((NDIM / BN) * (BATCH / BM));  // 512 linear, swizzled in-kernel
  for (int t = 1; t <= 16; t++) {
    const _Float16* ah = (t & 1) ? SAh : SBh;
    const _Float16* al = (t & 1) ? SAl : SBl;
    _Float16* dh = (t & 1) ? SBh : SAh;
    _Float16* dl = (t & 1) ? SBl : SAl;
    int klen = (t == 1) ? INDIM : NDIM;
    if (t < 16)
      step_kernel<0><<<grid, 256, 0, stream>>>(ah, al, Wth, Wtl, dh, dl, nullptr, klen);
    else
      step_kernel<1><<<grid, 256, 0, stream>>>(ah, al, Wth, Wtl, nullptr, nullptr, out, klen);
  }
}